// Round 10
// baseline (224.439 us; speedup 1.0000x reference)
//
#include <hip/hip_runtime.h>

#define NP 50000
#define NA 20000
#define E_W 250000
#define E_C 500000
#define E_R 250000
#define E_TOT (E_W + E_C + E_R)
#define CAP 48
#define RBLK 8192
#define NSEG 123            // ceil(E_TOT/RBLK)
#define NCHP 782            // paper chunks of 64 nodes (ceil 50000/64)
#define NCHA 313            // author chunks of 64 nodes (ceil 20000/64)
#define NBIN (NCHP + NCHA)  // 1095

typedef __attribute__((ext_vector_type(8))) short short8;
typedef __attribute__((ext_vector_type(4))) float floatx4;
typedef __attribute__((ext_vector_type(2))) float floatx2;

__device__ __forceinline__ unsigned short f2bf(float f) {
    unsigned u = __float_as_uint(f);
    return (unsigned short)((u + 0x7FFFu + ((u >> 16) & 1u)) >> 16);
}
__device__ __forceinline__ float bflo(unsigned v) { return __uint_as_float(v << 16); }
__device__ __forceinline__ float bfhi(unsigned v) { return __uint_as_float(v & 0xFFFF0000u); }

// frag layout for 16x16x32 bf16 B-operand: n=lane&15, k=quad*8+r
__device__ __forceinline__ int frag_off(int NT, int j, int n, int k) {
    int t = n >> 4, ln = n & 15;
    int kb = k >> 5, q = (k >> 3) & 3, r = k & 7;
    return (((j * NT + t) * 4 + kb) * 64 + q * 16 + ln) * 8 + r;
}

// ---------------- prep body: fp32->bf16 + fp32->fp8 + weight/bias prep ----------------
// Also zeroes the 4 dummy gather rows (replaces 4 hipMemsetAsync dispatches).
__device__ __forceinline__ void prep_body(
    int idx,
    const float* __restrict__ xp, const float* __restrict__ xa,
    const float* __restrict__ Wl1, const float* __restrict__ Wr1,
    const float* __restrict__ Wl2, const float* __restrict__ Wr2,
    const float* __restrict__ bl1, const float* __restrict__ bl2,
    unsigned short* __restrict__ xpb, unsigned short* __restrict__ xab,
    unsigned* __restrict__ xp8, unsigned* __restrict__ xa8,
    unsigned short* __restrict__ Wp1, unsigned short* __restrict__ Wa1,
    unsigned short* __restrict__ Wt2, unsigned short* __restrict__ Wr2s,
    float* __restrict__ bias_p1, float* __restrict__ bias_a1,
    float* __restrict__ bias_p2,
    unsigned short* __restrict__ ta, unsigned short* __restrict__ tp) {
    const int n4p = NP * 32, n4a = NA * 32;
    if (idx < n4p + n4a) {
        const float* s; unsigned short* d; unsigned* d8; int i = idx;
        if (i < n4p) { s = xp; d = xpb; d8 = xp8; }
        else { s = xa; d = xab; d8 = xa8; i -= n4p; }
        float4 v = ((const float4*)s)[i];
        ushort4 u;
        u.x = f2bf(v.x); u.y = f2bf(v.y); u.z = f2bf(v.z); u.w = f2bf(v.w);
        ((ushort4*)d)[i] = u;
        int w = __builtin_amdgcn_cvt_pk_fp8_f32(v.x, v.y, 0, false);
        w = __builtin_amdgcn_cvt_pk_fp8_f32(v.z, v.w, w, true);
        d8[i] = (unsigned)w;
        return;
    }
    int j = idx - (n4p + n4a);
    if (j < 49152) {  // Wp1: [j=3][n=128][k=128], 0.5 folded
        int jj = j >> 14, rem = j & 16383, n = rem >> 7, k = rem & 127;
        float v = (jj == 0)   ? 0.5f * Wl1[rem]
                  : (jj == 1) ? 0.5f * Wl1[16384 + rem]
                              : 0.5f * (Wr1[rem] + Wr1[16384 + rem]);
        Wp1[frag_off(8, jj, n, k)] = f2bf(v);
    } else if (j < 81920) {  // Wa1: [j=2][128][128]
        int i2 = j - 49152;
        int jj = i2 >> 14, rem = i2 & 16383, n = rem >> 7, k = rem & 127;
        float v = (jj == 0) ? Wl1[2 * 16384 + rem] : Wr1[2 * 16384 + rem];
        Wa1[frag_off(8, jj, n, k)] = f2bf(v);
    } else if (j < 98304) {  // Wt2: [j=2][n=64][k=128], 0.5 folded
        int i2 = j - 81920;
        int jj = i2 >> 13, rem = i2 & 8191, n = rem >> 7, k = rem & 127;
        float v = 0.5f * Wl2[jj * 8192 + rem];
        Wt2[frag_off(4, jj, n, k)] = f2bf(v);
    } else if (j < 106496) {  // Wr2s: [n=64][k=128] = 0.5*(Wr2_0+Wr2_1)
        int i2 = j - 98304;
        int n = i2 >> 7, k = i2 & 127;
        float v = 0.5f * (Wr2[i2] + Wr2[8192 + i2]);
        Wr2s[frag_off(4, 0, n, k)] = f2bf(v);
    } else if (j < 106496 + 320) {
        int b = j - 106496;
        if (b < 128) bias_p1[b] = 0.5f * (bl1[b] + bl1[128 + b]);
        else if (b < 256) bias_a1[b - 128] = bl1[256 + b - 128];
        else bias_p2[b - 256] = 0.5f * (bl2[b - 256] + bl2[64 + b - 256]);
    } else if (j < 106496 + 320 + 128) {  // dummy zero rows (was 4 memset dispatches)
        int b = j - (106496 + 320);
        if (b < 32) xp8[NP * 32 + b] = 0;
        else if (b < 64) xa8[NA * 32 + (b - 32)] = 0;
        else if (b < 96) ((unsigned*)ta)[NA * 32 + (b - 64)] = 0;
        else ((unsigned*)tp)[NP * 32 + (b - 96)] = 0;
    }
}

// ---------------- edge -> (bin, sub, src) mapping --------------------------------------
// bin = 64-node dst chunk; paper bins hold BOTH relations (sub: writes 0-63, cites 64-127)
__device__ __forceinline__ void edge_bin(
    int e, const int* __restrict__ w_src, const int* __restrict__ w_dst,
    const int* __restrict__ c_src, const int* __restrict__ c_dst,
    const int* __restrict__ r_src, const int* __restrict__ r_dst,
    int& bin, int& sub, int& src) {
    bool isC = (e >= E_W) & (e < E_W + E_C);
    bool isR = e >= E_W + E_C;
    const int* db = isR ? r_dst : (isC ? c_dst : w_dst);
    const int* sb = isR ? r_src : (isC ? c_src : w_src);
    int idx = e - (isC ? E_W : 0) - (isR ? (E_W + E_C) : 0);
    int d = db[idx];
    src = sb[idx];
    if (isR) { bin = NCHP + (d >> 6); sub = d & 63; }
    else { bin = d >> 6; sub = (d & 63) + (isC ? 64 : 0); }
}

// ---------------- route body: 2-pass LDS-histogram binning (no global atomics) ---------
// Pass 1 register-carries (bin,sub,src) for all 16 edges (fully unrolled, static
// indexing) so pass 2 needs no edge re-read and no edge_bin recompute.
__device__ __forceinline__ void route_body(
    int bid, const int* __restrict__ w_src, const int* __restrict__ w_dst,
    const int* __restrict__ c_src, const int* __restrict__ c_dst,
    const int* __restrict__ r_src, const int* __restrict__ r_dst,
    unsigned* __restrict__ seg, unsigned* __restrict__ segmeta,
    int* cnt_s, int* base_s, int* cur_s) {
    int tid = threadIdx.x, lane = tid & 63;
    for (int k = tid; k < NBIN; k += 512) cnt_s[k] = 0;
    __syncthreads();
    // pass 1: histogram + register-carry (8192 edges per block, 16/thread)
    unsigned pk[16];   // src | sub<<16
    unsigned bin2[8];  // two 16-bit bins per reg; 0xFFFF = invalid edge
#pragma unroll
    for (int u = 0; u < 16; ++u) {
        int e = bid * RBLK + u * 512 + tid;
        int bin = 0xFFFF, sub = 0, src = 0;
        if (e < E_TOT) {
            edge_bin(e, w_src, w_dst, c_src, c_dst, r_src, r_dst, bin, sub, src);
            atomicAdd(&cnt_s[bin], 1);
        }
        pk[u] = (unsigned)src | ((unsigned)sub << 16);
        if ((u & 1) == 0) bin2[u >> 1] = (unsigned)bin;
        else bin2[u >> 1] |= (unsigned)bin << 16;
    }
    __syncthreads();
    // exclusive scan over 1095 bins (wave 0; 18 bins/lane)
    if (tid < 64) {
        int v[18], tot = 0;
#pragma unroll
        for (int q = 0; q < 18; ++q) {
            int k = tid * 18 + q;
            v[q] = (k < NBIN) ? cnt_s[k] : 0;
            tot += v[q];
        }
        int sc = tot;
#pragma unroll
        for (int ofs = 1; ofs < 64; ofs <<= 1) {
            int t = __shfl_up(sc, ofs, 64);
            if (lane >= ofs) sc += t;
        }
        int run = sc - tot;
#pragma unroll
        for (int q = 0; q < 18; ++q) {
            int k = tid * 18 + q;
            if (k < NBIN) { base_s[k] = run; run += v[q]; }
        }
    }
    __syncthreads();
    for (int k = tid; k < NBIN; k += 512) {
        segmeta[bid * NBIN + k] = ((unsigned)base_s[k] << 16) | (unsigned)cnt_s[k];
        cur_s[k] = base_s[k];
    }
    __syncthreads();
    // pass 2: place from carried registers (no edge re-read)
    unsigned* segb = seg + (size_t)bid * RBLK;
#pragma unroll
    for (int u = 0; u < 16; ++u) {
        unsigned bin = (bin2[u >> 1] >> ((u & 1) * 16)) & 0xFFFFu;
        if (bin != 0xFFFFu) {
            int pos = atomicAdd(&cur_s[bin], 1);
            segb[pos] = pk[u];
        }
    }
}

// ---------------- combined route + prep (independent work, co-scheduled) ---------------
__global__ __launch_bounds__(512) void route_prep(
    const float* xp, const float* xa, const float* Wl1, const float* Wr1,
    const float* Wl2, const float* Wr2, const float* bl1, const float* bl2,
    unsigned short* xpb, unsigned short* xab, unsigned* xp8, unsigned* xa8,
    unsigned short* Wp1, unsigned short* Wa1, unsigned short* Wt2, unsigned short* Wr2s,
    float* bias_p1, float* bias_a1, float* bias_p2,
    const int* w_src, const int* w_dst, const int* c_src, const int* c_dst,
    const int* r_src, const int* r_dst,
    unsigned* seg, unsigned* segmeta,
    unsigned short* ta, unsigned short* tp) {
    __shared__ int cnt_s[NBIN], base_s[NBIN], cur_s[NBIN];
    if ((int)blockIdx.x < NSEG)
        route_body(blockIdx.x, w_src, w_dst, c_src, c_dst, r_src, r_dst,
                   seg, segmeta, cnt_s, base_s, cur_s);
    else
        prep_body((blockIdx.x - NSEG) * 512 + threadIdx.x, xp, xa, Wl1, Wr1, Wl2, Wr2,
                  bl1, bl2, xpb, xab, xp8, xa8, Wp1, Wa1, Wt2, Wr2s,
                  bias_p1, bias_a1, bias_p2, ta, tp);
}

// ---------------- fused CSR build + layer-1 aggregation + layer-1 GEMM + transforms ----
// rows/aggL now UNION one LDS buffer (lifetimes made disjoint by gathering into
// registers: 8x uint2 carry, written back after a barrier). LDS 48.1K -> ~35.8K
// => 4 blocks/CU (was 3) and near-single-round grid (1024 of 1095 concurrent).
// __launch_bounds__(512,8) pins VGPR <= 64 (the 8-waves/SIMD cliff).
// csr/cnt spill moved BEFORE the gather (reads rows while still live; stores drain
// for free under the ~30us gather).
__global__ __launch_bounds__(512, 8) void fill_l1(
    const unsigned* __restrict__ seg, const unsigned* __restrict__ segmeta,
    int* __restrict__ cnt, unsigned short* __restrict__ csr,
    const unsigned* __restrict__ xp8, const unsigned* __restrict__ xa8,
    const unsigned short* __restrict__ xpb, const unsigned short* __restrict__ xab,
    const unsigned short* __restrict__ Wp1, const float* __restrict__ bias_p1,
    const unsigned short* __restrict__ Wa1, const float* __restrict__ bias_a1,
    const unsigned short* __restrict__ Wt2, const unsigned short* __restrict__ Wr2s,
    unsigned short* __restrict__ ta, unsigned short* __restrict__ tp,
    float* __restrict__ sp) {
    __shared__ __align__(16) unsigned char uni[128 * 136 * 2];  // 34816 B: rows ∪ aggL
    __shared__ int cursor[128];
    __shared__ unsigned pkd[NSEG];
    unsigned short* rows = (unsigned short*)uni;                 // [128*CAP] (12288 B)
    typedef unsigned short aggrow_t[136];
    aggrow_t* aggL = (aggrow_t*)uni;                             // [128][136]
    int tid = threadIdx.x;
    int k = blockIdx.x;
    bool isPaper = k < NCHP;
    int base = isPaper ? k * 64 : (k - NCHP) * 64;
    int total = isPaper ? NP : NA;
    int M = total - base; if (M > 64) M = 64;

    for (int s = tid; s < NSEG; s += 512) pkd[s] = segmeta[s * NBIN + k];
    if (tid < 128) cursor[tid] = 0;
    __syncthreads();
    // ---- fill: 32 groups of 16 lanes walk segments (~4 each) ----
    {
        int grp = tid >> 4, gl = tid & 15;
        for (int s = grp; s < NSEG; s += 32) {
            unsigned pk = pkd[s];
            int n = pk & 0xFFFFu;
            const unsigned* spq = seg + (size_t)s * RBLK + (pk >> 16);
            for (int i = gl; i < n; i += 16) {
                unsigned v = spq[i];
                int sub = v >> 16, srcn = v & 0xFFFFu;
                int pos = atomicAdd(&cursor[sub], 1);
                if (pos < CAP) rows[sub * CAP + pos] = (unsigned short)srcn;
            }
        }
    }
    __syncthreads();
    // ---- spill cnt/csr node-major for paper (reads rows BEFORE aggL overwrites it;
    //      stores complete in the background during the gather) ----
    if (isPaper) {
        for (int r = tid; r < 2 * M; r += 512)
            cnt[base * 2 + r] = cursor[(r >> 1) + ((r & 1) << 6)];
        const unsigned* rU = (const unsigned*)rows;
        unsigned* cU = (unsigned*)csr + (size_t)base * 2 * (CAP / 2);
        for (int i = tid; i < 2 * M * (CAP / 2); i += 512) {
            int r = i / (CAP / 2), j = i - r * (CAP / 2);
            cU[i] = rU[((r >> 1) + ((r & 1) << 6)) * (CAP / 2) + j];
        }
    }
    // ---- merged gather (both relations), dual-row, packed-f32 accumulation, results
    //      carried in registers until rows is dead ----
    int g = tid >> 5, sl = tid & 31;
    auto grow2 = [&](int l0, const unsigned* __restrict__ s0,
                     const unsigned* __restrict__ s1, int d0, int d1,
                     uint2& oA, uint2& oB) {
        int lA = l0, lB = l0 + 16;
        const unsigned* sA = (lA & 64) ? s1 : s0;
        const unsigned* sB = (lB & 64) ? s1 : s0;
        int duA = (lA & 64) ? d1 : d0;
        int duB = (lB & 64) ? d1 : d0;
        int dA = cursor[lA], dB = cursor[lB];
        int cA = dA < CAP ? dA : CAP, cB = dB < CAP ? dB : CAP;
        int cm = cA > cB ? cA : cB;
        const unsigned short* rpA = &rows[lA * CAP];
        const unsigned short* rpB = &rows[lB * CAP];
        floatx2 eA0 = {0.f, 0.f}, eA1 = {0.f, 0.f};
        floatx2 oA0 = {0.f, 0.f}, oA1 = {0.f, 0.f};
        floatx2 eB0 = {0.f, 0.f}, eB1 = {0.f, 0.f};
        floatx2 oB0 = {0.f, 0.f}, oB1 = {0.f, 0.f};
        for (int i = 0; i < cm; i += 8) {
            short8 rA = *(const short8*)&rpA[i];  // broadcast ds_read_b128
            short8 rB = *(const short8*)&rpB[i];
            unsigned vA[8], vB[8];
#pragma unroll
            for (int u = 0; u < 8; ++u) {
                int q = (i + u < cA) ? (int)(unsigned short)rA[u] : duA;
                vA[u] = sA[(q << 5) + sl];
            }
#pragma unroll
            for (int u = 0; u < 8; ++u) {
                int q = (i + u < cB) ? (int)(unsigned short)rB[u] : duB;
                vB[u] = sB[(q << 5) + sl];
            }
#pragma unroll
            for (int u = 0; u < 8; ++u) {
                floatx2 lo = __builtin_amdgcn_cvt_pk_f32_fp8(vA[u], false);
                floatx2 hi = __builtin_amdgcn_cvt_pk_f32_fp8(vA[u], true);
                if (u & 1) { oA0 += lo; oA1 += hi; }
                else       { eA0 += lo; eA1 += hi; }
            }
#pragma unroll
            for (int u = 0; u < 8; ++u) {
                floatx2 lo = __builtin_amdgcn_cvt_pk_f32_fp8(vB[u], false);
                floatx2 hi = __builtin_amdgcn_cvt_pk_f32_fp8(vB[u], true);
                if (u & 1) { oB0 += lo; oB1 += hi; }
                else       { eB0 += lo; eB1 += hi; }
            }
        }
        floatx2 sA0 = eA0 + oA0, sA1 = eA1 + oA1;
        floatx2 sB0 = eB0 + oB0, sB1 = eB1 + oB1;
        float sclA = dA > 0 ? 1.f / (float)dA : 0.f;
        float sclB = dB > 0 ? 1.f / (float)dB : 0.f;
        oA = make_uint2(((unsigned)f2bf(sA0.y * sclA) << 16) | (unsigned)f2bf(sA0.x * sclA),
                        ((unsigned)f2bf(sA1.y * sclA) << 16) | (unsigned)f2bf(sA1.x * sclA));
        oB = make_uint2(((unsigned)f2bf(sB0.y * sclB) << 16) | (unsigned)f2bf(sB0.x * sclB),
                        ((unsigned)f2bf(sB1.y * sclB) << 16) | (unsigned)f2bf(sB1.x * sclB));
    };
    if (isPaper) {
        uint2 oA[4], oB[4];
#pragma unroll
        for (int it = 0; it < 4; ++it)
            grow2(g + it * 32, xa8, xp8, NA, NP, oA[it], oB[it]);
        __syncthreads();   // all rows-reads complete; safe to overwrite union
#pragma unroll
        for (int it = 0; it < 4; ++it) {
            int l0 = g + it * 32;
            *(uint2*)&aggL[l0][sl * 4] = oA[it];
            *(uint2*)&aggL[l0 + 16][sl * 4] = oB[it];
        }
    } else {
        uint2 oA[2], oB[2];
#pragma unroll
        for (int it = 0; it < 2; ++it)
            grow2(g + it * 32, xp8, xp8, NP, NP, oA[it], oB[it]);
        __syncthreads();
#pragma unroll
        for (int it = 0; it < 2; ++it) {
            int l0 = g + it * 32;
            *(uint2*)&aggL[l0][sl * 4] = oA[it];
            *(uint2*)&aggL[l0 + 16][sl * 4] = oB[it];
        }
    }
    __syncthreads();
    // ---- GEMMs back-to-back ----
    int wave = tid >> 6, lane = tid & 63, ln = lane & 15, quad = lane >> 4;
    int wrow = (wave & 3) * 16, nhalf = wave >> 2;
    floatx4 acc[4];
#pragma unroll
    for (int t = 0; t < 4; ++t) acc[t] = (floatx4){0.f, 0.f, 0.f, 0.f};
    auto gemm_lds = [&](const unsigned short* __restrict__ Wb, int rowoff) {
#pragma unroll
        for (int kb = 0; kb < 4; ++kb) {
            short8 af = *(const short8*)&aggL[rowoff + wrow + ln][quad * 8 + kb * 32];
#pragma unroll
            for (int t = 0; t < 4; ++t) {
                short8 bf = *(const short8*)(Wb + ((nhalf * 4 + t) * 4 + kb) * 512 + lane * 8);
                acc[t] = __builtin_amdgcn_mfma_f32_16x16x32_bf16(af, bf, acc[t], 0, 0, 0);
            }
        }
    };
    auto gemm_glob = [&](const unsigned short* __restrict__ X,
                         const unsigned short* __restrict__ Wb) {
        int row = base + wrow + ln;
        int rowc = row < total ? row : total - 1;
        const unsigned short* A = X + (size_t)rowc * 128 + quad * 8;
#pragma unroll
        for (int kb = 0; kb < 4; ++kb) {
            short8 af = *(const short8*)(A + kb * 32);
#pragma unroll
            for (int t = 0; t < 4; ++t) {
                short8 bf = *(const short8*)(Wb + ((nhalf * 4 + t) * 4 + kb) * 512 + lane * 8);
                acc[t] = __builtin_amdgcn_mfma_f32_16x16x32_bf16(af, bf, acc[t], 0, 0, 0);
            }
        }
    };
    if (isPaper) {
        gemm_lds(Wp1, 0);                   // 0.5*Wl1[0] @ writes-agg (rows 0-63)
        gemm_lds(Wp1 + 16384, 64);          // 0.5*Wl1[1] @ cites-agg (rows 64-127)
        gemm_glob(xpb, Wp1 + 2 * 16384);    // 0.5*(Wr1[0]+Wr1[1]) @ x
    } else {
        gemm_lds(Wa1, 0);                   // Wl1[2] @ rev-agg
        gemm_glob(xab, Wa1 + 16384);        // Wr1[2] @ x
    }
    __syncthreads();
    // ---- epilogue: h = relu(acc + bias) -> aggL rows 0-63 (reused as hL) ----
    {
        const float* bias = isPaper ? bias_p1 : bias_a1;
#pragma unroll
        for (int t = 0; t < 4; ++t) {
            int col = nhalf * 64 + t * 16 + ln;
            float bv = bias[col];
#pragma unroll
            for (int r = 0; r < 4; ++r)
                aggL[wrow + quad * 4 + r][col] = f2bf(fmaxf(acc[t][r] + bv, 0.f));
        }
    }
    __syncthreads();
    // ---- transforms: t = h@Wt^T (+ sp = h@Wr2s^T for paper) ----
    floatx4 tacc[4];
#pragma unroll
    for (int t = 0; t < 4; ++t) tacc[t] = (floatx4){0.f, 0.f, 0.f, 0.f};
    int rows16 = (wave & 3) * 16;
    if (isPaper) {
        const unsigned short* W = (wave < 4) ? (Wt2 + 64 * 128) : Wr2s;
#pragma unroll
        for (int kb = 0; kb < 4; ++kb) {
            short8 af = *(const short8*)&aggL[rows16 + ln][quad * 8 + kb * 32];
#pragma unroll
            for (int t = 0; t < 4; ++t) {
                short8 bf = *(const short8*)(W + (t * 4 + kb) * 512 + lane * 8);
                tacc[t] = __builtin_amdgcn_mfma_f32_16x16x32_bf16(af, bf, tacc[t], 0, 0, 0);
            }
        }
#pragma unroll
        for (int t = 0; t < 4; ++t) {
            int col = t * 16 + ln;
#pragma unroll
            for (int r = 0; r < 4; ++r) {
                int lr = rows16 + quad * 4 + r;
                if (lr < M) {
                    if (wave < 4) tp[(size_t)(base + lr) * 64 + col] = f2bf(tacc[t][r]);
                    else sp[(size_t)(base + lr) * 64 + col] = tacc[t][r];
                }
            }
        }
    } else {
        int thalf = wave >> 2;
#pragma unroll
        for (int kb = 0; kb < 4; ++kb) {
            short8 af = *(const short8*)&aggL[rows16 + ln][quad * 8 + kb * 32];
#pragma unroll
            for (int tt = 0; tt < 2; ++tt) {
                short8 bf = *(const short8*)(Wt2 + ((thalf * 2 + tt) * 4 + kb) * 512 + lane * 8);
                tacc[tt] = __builtin_amdgcn_mfma_f32_16x16x32_bf16(af, bf, tacc[tt], 0, 0, 0);
            }
        }
#pragma unroll
        for (int tt = 0; tt < 2; ++tt) {
            int col = (thalf * 2 + tt) * 16 + ln;
#pragma unroll
            for (int r = 0; r < 4; ++r) {
                int lr = rows16 + quad * 4 + r;
                if (lr < M) ta[(size_t)(base + lr) * 64 + col] = f2bf(tacc[tt][r]);
            }
        }
    }
}

// ---------------- layer-2 aggregation + final epilogue: out = agg + sp + bias ----------
// Both relations merged (16 loads in flight/lane) + packed-f32 accumulation.
__global__ void agg2(const unsigned short* __restrict__ ta, const unsigned short* __restrict__ tp,
                     const int* __restrict__ cnt, const unsigned short* __restrict__ csr,
                     const float* __restrict__ sp_in, const float* __restrict__ bias_p2,
                     float* __restrict__ out) {
    int node = blockIdx.x * 8 + (threadIdx.x >> 5);
    if (node >= NP) return;
    int lane = threadIdx.x & 63;
    int sl = lane & 31;
    int hw = lane & 32;
    const unsigned* t0p = (const unsigned*)ta;
    const unsigned* t1p = (const unsigned*)tp;
    int deg0 = cnt[node * 2], deg1 = cnt[node * 2 + 1];
    int c0 = deg0 < CAP ? deg0 : CAP;
    int c1 = deg1 < CAP ? deg1 : CAP;
    const unsigned short* row0 = csr + (size_t)node * 2 * CAP;
    const unsigned short* row1 = row0 + CAP;
    int e00 = (sl < c0) ? (int)row0[sl] : NA;
    int e01 = (32 + sl < c0) ? (int)row0[32 + sl] : NA;
    int e10 = (sl < c1) ? (int)row1[sl] : NP;
    int e11 = (32 + sl < c1) ? (int)row1[32 + sl] : NP;
    int degw = c0 > c1 ? c0 : c1;
    int other = __shfl_xor(degw, 32, 64);
    if (other > degw) degw = other;
    floatx2 se = {0.f, 0.f}, so = {0.f, 0.f};   // rel0 even/odd chains (lo, hi)
    floatx2 ue = {0.f, 0.f}, uo = {0.f, 0.f};   // rel1 even/odd chains
    for (int i = 0; i < degw; i += 8) {
        unsigned v0[8], v1[8];
#pragma unroll
        for (int u = 0; u < 8; ++u) {
            int ii = i + u;
            int es = (ii < 32) ? e00 : e01;
            int qq = __shfl(es, hw | (ii & 31), 64);
            qq = (ii < c0) ? qq : NA;
            v0[u] = t0p[(qq << 5) + sl];
        }
#pragma unroll
        for (int u = 0; u < 8; ++u) {
            int ii = i + u;
            int es = (ii < 32) ? e10 : e11;
            int qq = __shfl(es, hw | (ii & 31), 64);
            qq = (ii < c1) ? qq : NP;
            v1[u] = t1p[(qq << 5) + sl];
        }
#pragma unroll
        for (int u = 0; u < 8; ++u) {
            floatx2 t = {bflo(v0[u]), bfhi(v0[u])};
            if (u & 1) so += t; else se += t;
        }
#pragma unroll
        for (int u = 0; u < 8; ++u) {
            floatx2 t = {bflo(v1[u]), bfhi(v1[u])};
            if (u & 1) uo += t; else ue += t;
        }
    }
    float scl0 = deg0 > 0 ? 1.f / (float)deg0 : 0.f;
    float scl1 = deg1 > 0 ? 1.f / (float)deg1 : 0.f;
    floatx2 s = se + so, u2 = ue + uo;
    float r0 = s.x * scl0 + u2.x * scl1;
    float r1 = s.y * scl0 + u2.y * scl1;
    float2 spv = ((const float2*)sp_in)[(size_t)node * 32 + sl];
    float2 bv = ((const float2*)bias_p2)[sl];
    ((float2*)out)[(size_t)node * 32 + sl] =
        make_float2(r0 + spv.x + bv.x, r1 + spv.y + bv.y);
}

// ---------------- launch ----------------
extern "C" void kernel_launch(void* const* d_in, const int* in_sizes, int n_in,
                              void* d_out, int out_size, void* d_ws, size_t ws_size,
                              hipStream_t stream) {
    (void)in_sizes; (void)n_in; (void)out_size; (void)ws_size;
    const float* xp  = (const float*)d_in[0];
    const float* xa  = (const float*)d_in[1];
    const float* Wl1 = (const float*)d_in[2];
    const float* bl1 = (const float*)d_in[3];
    const float* Wr1 = (const float*)d_in[4];
    const float* Wl2 = (const float*)d_in[5];
    const float* bl2 = (const float*)d_in[6];
    const float* Wr2 = (const float*)d_in[7];
    const int* w_src = (const int*)d_in[8];
    const int* w_dst = (const int*)d_in[9];
    const int* c_src = (const int*)d_in[10];
    const int* c_dst = (const int*)d_in[11];
    const int* r_src = (const int*)d_in[12];
    const int* r_dst = (const int*)d_in[13];
    float* out = (float*)d_out;

    char* p = (char*)d_ws;
    auto alloc = [&](size_t bytes) {
        char* r = p;
        p += (bytes + 255) & ~(size_t)255;
        return r;
    };
    unsigned short* xpb   = (unsigned short*)alloc((size_t)NP * 128 * 2);
    unsigned short* xab   = (unsigned short*)alloc((size_t)NA * 128 * 2);
    unsigned*       xp8   = (unsigned*)alloc((size_t)(NP + 1) * 128);  // +1 dummy zero row
    unsigned*       xa8   = (unsigned*)alloc((size_t)(NA + 1) * 128);  // +1 dummy zero row
    unsigned short* ta    = (unsigned short*)alloc((size_t)(NA + 1) * 64 * 2);  // +1 dummy
    unsigned short* tp    = (unsigned short*)alloc((size_t)(NP + 1) * 64 * 2);  // +1 dummy
    float*          sp    = (float*)alloc((size_t)NP * 64 * 4);
    int*            cnt     = (int*)alloc((size_t)NP * 2 * 4);
    unsigned short* csr     = (unsigned short*)alloc((size_t)NP * 2 * CAP * 2);
    unsigned*       seg     = (unsigned*)alloc((size_t)NSEG * RBLK * 4);
    unsigned*       segmeta = (unsigned*)alloc((size_t)NSEG * NBIN * 4);
    unsigned short* Wp1  = (unsigned short*)alloc(3 * 128 * 128 * 2);
    unsigned short* Wa1  = (unsigned short*)alloc(2 * 128 * 128 * 2);
    unsigned short* Wt2  = (unsigned short*)alloc(2 * 64 * 128 * 2);
    unsigned short* Wr2s = (unsigned short*)alloc(64 * 128 * 2);
    float* bias_p1 = (float*)alloc(128 * 4);
    float* bias_a1 = (float*)alloc(128 * 4);
    float* bias_p2 = (float*)alloc(64 * 4);

    // route (123 blocks @512 thr) + prep (incl. dummy-row zeroing) in one kernel
    int prep_threads = (NP + NA) * 32 + 106496 + 320 + 128;
    int prep_blocks = (prep_threads + 511) / 512;
    route_prep<<<NSEG + prep_blocks, 512, 0, stream>>>(
        xp, xa, Wl1, Wr1, Wl2, Wr2, bl1, bl2,
        xpb, xab, xp8, xa8, Wp1, Wa1, Wt2, Wr2s, bias_p1, bias_a1, bias_p2,
        w_src, w_dst, c_src, c_dst, r_src, r_dst, seg, segmeta, ta, tp);

    // fused CSR build + layer-1 agg + layer-1 GEMM + transforms (4 blocks/CU)
    fill_l1<<<NBIN, 512, 0, stream>>>(seg, segmeta, cnt, csr,
                                      xp8, xa8, xpb, xab, Wp1, bias_p1, Wa1, bias_a1,
                                      Wt2, Wr2s, ta, tp, sp);

    // layer-2 aggregation + final epilogue -> out
    agg2<<<(NP + 7) / 8, 256, 0, stream>>>(ta, tp, cnt, csr, sp, bias_p2, out);
}

// Round 11
// 184.109 us; speedup vs baseline: 1.2191x; 1.2191x over previous
//
#include <hip/hip_runtime.h>

#define NP 50000
#define NA 20000
#define E_W 250000
#define E_C 500000
#define E_R 250000
#define E_TOT (E_W + E_C + E_R)
#define CAP 48
#define RBLK 8192
#define NSEG 123            // ceil(E_TOT/RBLK)
#define NCHP 782            // paper chunks of 64 nodes (ceil 50000/64)
#define NCHA 313            // author chunks of 64 nodes (ceil 20000/64)
#define NBIN (NCHP + NCHA)  // 1095

typedef __attribute__((ext_vector_type(8))) short short8;
typedef __attribute__((ext_vector_type(4))) float floatx4;
typedef __attribute__((ext_vector_type(2))) float floatx2;

__device__ __forceinline__ unsigned short f2bf(float f) {
    unsigned u = __float_as_uint(f);
    return (unsigned short)((u + 0x7FFFu + ((u >> 16) & 1u)) >> 16);
}
__device__ __forceinline__ float bflo(unsigned v) { return __uint_as_float(v << 16); }
__device__ __forceinline__ float bfhi(unsigned v) { return __uint_as_float(v & 0xFFFF0000u); }

// frag layout for 16x16x32 bf16 B-operand: n=lane&15, k=quad*8+r
__device__ __forceinline__ int frag_off(int NT, int j, int n, int k) {
    int t = n >> 4, ln = n & 15;
    int kb = k >> 5, q = (k >> 3) & 3, r = k & 7;
    return (((j * NT + t) * 4 + kb) * 64 + q * 16 + ln) * 8 + r;
}

// ---------------- prep body: fp32->bf16 + fp32->fp8 + weight/bias prep ----------------
// Also zeroes the 4 dummy gather rows (replaces 4 hipMemsetAsync dispatches).
__device__ __forceinline__ void prep_body(
    int idx,
    const float* __restrict__ xp, const float* __restrict__ xa,
    const float* __restrict__ Wl1, const float* __restrict__ Wr1,
    const float* __restrict__ Wl2, const float* __restrict__ Wr2,
    const float* __restrict__ bl1, const float* __restrict__ bl2,
    unsigned short* __restrict__ xpb, unsigned short* __restrict__ xab,
    unsigned* __restrict__ xp8, unsigned* __restrict__ xa8,
    unsigned short* __restrict__ Wp1, unsigned short* __restrict__ Wa1,
    unsigned short* __restrict__ Wt2, unsigned short* __restrict__ Wr2s,
    float* __restrict__ bias_p1, float* __restrict__ bias_a1,
    float* __restrict__ bias_p2,
    unsigned short* __restrict__ ta, unsigned short* __restrict__ tp) {
    const int n4p = NP * 32, n4a = NA * 32;
    if (idx < n4p + n4a) {
        const float* s; unsigned short* d; unsigned* d8; int i = idx;
        if (i < n4p) { s = xp; d = xpb; d8 = xp8; }
        else { s = xa; d = xab; d8 = xa8; i -= n4p; }
        float4 v = ((const float4*)s)[i];
        ushort4 u;
        u.x = f2bf(v.x); u.y = f2bf(v.y); u.z = f2bf(v.z); u.w = f2bf(v.w);
        ((ushort4*)d)[i] = u;
        int w = __builtin_amdgcn_cvt_pk_fp8_f32(v.x, v.y, 0, false);
        w = __builtin_amdgcn_cvt_pk_fp8_f32(v.z, v.w, w, true);
        d8[i] = (unsigned)w;
        return;
    }
    int j = idx - (n4p + n4a);
    if (j < 49152) {  // Wp1: [j=3][n=128][k=128], 0.5 folded
        int jj = j >> 14, rem = j & 16383, n = rem >> 7, k = rem & 127;
        float v = (jj == 0)   ? 0.5f * Wl1[rem]
                  : (jj == 1) ? 0.5f * Wl1[16384 + rem]
                              : 0.5f * (Wr1[rem] + Wr1[16384 + rem]);
        Wp1[frag_off(8, jj, n, k)] = f2bf(v);
    } else if (j < 81920) {  // Wa1: [j=2][128][128]
        int i2 = j - 49152;
        int jj = i2 >> 14, rem = i2 & 16383, n = rem >> 7, k = rem & 127;
        float v = (jj == 0) ? Wl1[2 * 16384 + rem] : Wr1[2 * 16384 + rem];
        Wa1[frag_off(8, jj, n, k)] = f2bf(v);
    } else if (j < 98304) {  // Wt2: [j=2][n=64][k=128], 0.5 folded
        int i2 = j - 81920;
        int jj = i2 >> 13, rem = i2 & 8191, n = rem >> 7, k = rem & 127;
        float v = 0.5f * Wl2[jj * 8192 + rem];
        Wt2[frag_off(4, jj, n, k)] = f2bf(v);
    } else if (j < 106496) {  // Wr2s: [n=64][k=128] = 0.5*(Wr2_0+Wr2_1)
        int i2 = j - 98304;
        int n = i2 >> 7, k = i2 & 127;
        float v = 0.5f * (Wr2[i2] + Wr2[8192 + i2]);
        Wr2s[frag_off(4, 0, n, k)] = f2bf(v);
    } else if (j < 106496 + 320) {
        int b = j - 106496;
        if (b < 128) bias_p1[b] = 0.5f * (bl1[b] + bl1[128 + b]);
        else if (b < 256) bias_a1[b - 128] = bl1[256 + b - 128];
        else bias_p2[b - 256] = 0.5f * (bl2[b - 256] + bl2[64 + b - 256]);
    } else if (j < 106496 + 320 + 128) {  // dummy zero rows (was 4 memset dispatches)
        int b = j - (106496 + 320);
        if (b < 32) xp8[NP * 32 + b] = 0;
        else if (b < 64) xa8[NA * 32 + (b - 32)] = 0;
        else if (b < 96) ((unsigned*)ta)[NA * 32 + (b - 64)] = 0;
        else ((unsigned*)tp)[NP * 32 + (b - 96)] = 0;
    }
}

// ---------------- edge -> (bin, sub, src) mapping --------------------------------------
// bin = 64-node dst chunk; paper bins hold BOTH relations (sub: writes 0-63, cites 64-127)
__device__ __forceinline__ void edge_bin(
    int e, const int* __restrict__ w_src, const int* __restrict__ w_dst,
    const int* __restrict__ c_src, const int* __restrict__ c_dst,
    const int* __restrict__ r_src, const int* __restrict__ r_dst,
    int& bin, int& sub, int& src) {
    bool isC = (e >= E_W) & (e < E_W + E_C);
    bool isR = e >= E_W + E_C;
    const int* db = isR ? r_dst : (isC ? c_dst : w_dst);
    const int* sb = isR ? r_src : (isC ? c_src : w_src);
    int idx = e - (isC ? E_W : 0) - (isR ? (E_W + E_C) : 0);
    int d = db[idx];
    src = sb[idx];
    if (isR) { bin = NCHP + (d >> 6); sub = d & 63; }
    else { bin = d >> 6; sub = (d & 63) + (isC ? 64 : 0); }
}

// ---------------- route body: 2-pass LDS-histogram binning (no global atomics) ---------
// Pass 1 register-carries (bin,sub,src) for all 16 edges (fully unrolled, static
// indexing) so pass 2 needs no edge re-read and no edge_bin recompute.
__device__ __forceinline__ void route_body(
    int bid, const int* __restrict__ w_src, const int* __restrict__ w_dst,
    const int* __restrict__ c_src, const int* __restrict__ c_dst,
    const int* __restrict__ r_src, const int* __restrict__ r_dst,
    unsigned* __restrict__ seg, unsigned* __restrict__ segmeta,
    int* cnt_s, int* base_s, int* cur_s) {
    int tid = threadIdx.x, lane = tid & 63;
    for (int k = tid; k < NBIN; k += 512) cnt_s[k] = 0;
    __syncthreads();
    // pass 1: histogram + register-carry (8192 edges per block, 16/thread)
    unsigned pk[16];   // src | sub<<16
    unsigned bin2[8];  // two 16-bit bins per reg; 0xFFFF = invalid edge
#pragma unroll
    for (int u = 0; u < 16; ++u) {
        int e = bid * RBLK + u * 512 + tid;
        int bin = 0xFFFF, sub = 0, src = 0;
        if (e < E_TOT) {
            edge_bin(e, w_src, w_dst, c_src, c_dst, r_src, r_dst, bin, sub, src);
            atomicAdd(&cnt_s[bin], 1);
        }
        pk[u] = (unsigned)src | ((unsigned)sub << 16);
        if ((u & 1) == 0) bin2[u >> 1] = (unsigned)bin;
        else bin2[u >> 1] |= (unsigned)bin << 16;
    }
    __syncthreads();
    // exclusive scan over 1095 bins (wave 0; 18 bins/lane)
    if (tid < 64) {
        int v[18], tot = 0;
#pragma unroll
        for (int q = 0; q < 18; ++q) {
            int k = tid * 18 + q;
            v[q] = (k < NBIN) ? cnt_s[k] : 0;
            tot += v[q];
        }
        int sc = tot;
#pragma unroll
        for (int ofs = 1; ofs < 64; ofs <<= 1) {
            int t = __shfl_up(sc, ofs, 64);
            if (lane >= ofs) sc += t;
        }
        int run = sc - tot;
#pragma unroll
        for (int q = 0; q < 18; ++q) {
            int k = tid * 18 + q;
            if (k < NBIN) { base_s[k] = run; run += v[q]; }
        }
    }
    __syncthreads();
    for (int k = tid; k < NBIN; k += 512) {
        segmeta[bid * NBIN + k] = ((unsigned)base_s[k] << 16) | (unsigned)cnt_s[k];
        cur_s[k] = base_s[k];
    }
    __syncthreads();
    // pass 2: place from carried registers (no edge re-read)
    unsigned* segb = seg + (size_t)bid * RBLK;
#pragma unroll
    for (int u = 0; u < 16; ++u) {
        unsigned bin = (bin2[u >> 1] >> ((u & 1) * 16)) & 0xFFFFu;
        if (bin != 0xFFFFu) {
            int pos = atomicAdd(&cur_s[bin], 1);
            segb[pos] = pk[u];
        }
    }
}

// ---------------- combined route + prep (independent work, co-scheduled) ---------------
__global__ __launch_bounds__(512) void route_prep(
    const float* xp, const float* xa, const float* Wl1, const float* Wr1,
    const float* Wl2, const float* Wr2, const float* bl1, const float* bl2,
    unsigned short* xpb, unsigned short* xab, unsigned* xp8, unsigned* xa8,
    unsigned short* Wp1, unsigned short* Wa1, unsigned short* Wt2, unsigned short* Wr2s,
    float* bias_p1, float* bias_a1, float* bias_p2,
    const int* w_src, const int* w_dst, const int* c_src, const int* c_dst,
    const int* r_src, const int* r_dst,
    unsigned* seg, unsigned* segmeta,
    unsigned short* ta, unsigned short* tp) {
    __shared__ int cnt_s[NBIN], base_s[NBIN], cur_s[NBIN];
    if ((int)blockIdx.x < NSEG)
        route_body(blockIdx.x, w_src, w_dst, c_src, c_dst, r_src, r_dst,
                   seg, segmeta, cnt_s, base_s, cur_s);
    else
        prep_body((blockIdx.x - NSEG) * 512 + threadIdx.x, xp, xa, Wl1, Wr1, Wl2, Wr2,
                  bl1, bl2, xpb, xab, xp8, xa8, Wp1, Wa1, Wt2, Wr2s,
                  bias_p1, bias_a1, bias_p2, ta, tp);
}

// ---------------- fused CSR build + layer-1 aggregation + layer-1 GEMM + transforms ----
// R9 form (best measured: 53.5us, VGPR 40, occ 45%): dual-row merged gather with
// packed-f32 accumulation, separate rows/aggL LDS. R10's rows∪aggL union REGRESSED
// (launch_bounds cap -> register-carry spilled to scratch: WRITE_SIZE 31->139MB,
// 90us). Do NOT re-attempt LDS union without a spill-free handoff.
__global__ __launch_bounds__(512) void fill_l1(
    const unsigned* __restrict__ seg, const unsigned* __restrict__ segmeta,
    int* __restrict__ cnt, unsigned short* __restrict__ csr,
    const unsigned* __restrict__ xp8, const unsigned* __restrict__ xa8,
    const unsigned short* __restrict__ xpb, const unsigned short* __restrict__ xab,
    const unsigned short* __restrict__ Wp1, const float* __restrict__ bias_p1,
    const unsigned short* __restrict__ Wa1, const float* __restrict__ bias_a1,
    const unsigned short* __restrict__ Wt2, const unsigned short* __restrict__ Wr2s,
    unsigned short* __restrict__ ta, unsigned short* __restrict__ tp,
    float* __restrict__ sp) {
    __shared__ unsigned short rows[128 * CAP];              // 12288 B
    __shared__ int cursor[128];
    __shared__ unsigned pkd[NSEG];
    __shared__ __align__(16) unsigned short aggL[128][136]; // 34816 B (pad: MFMA A-reads)
    int tid = threadIdx.x;
    int k = blockIdx.x;
    bool isPaper = k < NCHP;
    int base = isPaper ? k * 64 : (k - NCHP) * 64;
    int total = isPaper ? NP : NA;
    int M = total - base; if (M > 64) M = 64;

    for (int s = tid; s < NSEG; s += 512) pkd[s] = segmeta[s * NBIN + k];
    if (tid < 128) cursor[tid] = 0;
    __syncthreads();
    // ---- fill: 32 groups of 16 lanes walk segments (~4 each) ----
    {
        int grp = tid >> 4, gl = tid & 15;
        for (int s = grp; s < NSEG; s += 32) {
            unsigned pk = pkd[s];
            int n = pk & 0xFFFFu;
            const unsigned* spq = seg + (size_t)s * RBLK + (pk >> 16);
            for (int i = gl; i < n; i += 16) {
                unsigned v = spq[i];
                int sub = v >> 16, srcn = v & 0xFFFFu;
                int pos = atomicAdd(&cursor[sub], 1);
                if (pos < CAP) rows[sub * CAP + pos] = (unsigned short)srcn;
            }
        }
    }
    __syncthreads();
    // ---- merged gather (both relations), dual-row, packed-f32 accumulation ----
    {
        const unsigned* s0 = isPaper ? xa8 : xp8;
        const unsigned* s1 = xp8;
        int d0 = isPaper ? NA : NP, d1 = NP;
        int LROWS = isPaper ? 128 : 64;
        int g = tid >> 5, sl = tid & 31;
        for (int l0 = g; l0 < LROWS; l0 += 32) {
            int lA = l0, lB = l0 + 16;
            const unsigned* sA = (lA & 64) ? s1 : s0;
            const unsigned* sB = (lB & 64) ? s1 : s0;
            int duA = (lA & 64) ? d1 : d0;
            int duB = (lB & 64) ? d1 : d0;
            int dA = cursor[lA], dB = cursor[lB];
            int cA = dA < CAP ? dA : CAP, cB = dB < CAP ? dB : CAP;
            int cm = cA > cB ? cA : cB;
            const unsigned short* rpA = &rows[lA * CAP];
            const unsigned short* rpB = &rows[lB * CAP];
            floatx2 eA0 = {0.f, 0.f}, eA1 = {0.f, 0.f};   // even-u chains (lo, hi)
            floatx2 oA0 = {0.f, 0.f}, oA1 = {0.f, 0.f};   // odd-u chains
            floatx2 eB0 = {0.f, 0.f}, eB1 = {0.f, 0.f};
            floatx2 oB0 = {0.f, 0.f}, oB1 = {0.f, 0.f};
            for (int i = 0; i < cm; i += 8) {
                short8 rA = *(const short8*)&rpA[i];  // broadcast ds_read_b128
                short8 rB = *(const short8*)&rpB[i];
                unsigned vA[8], vB[8];
#pragma unroll
                for (int u = 0; u < 8; ++u) {
                    int q = (i + u < cA) ? (int)(unsigned short)rA[u] : duA;
                    vA[u] = sA[(q << 5) + sl];
                }
#pragma unroll
                for (int u = 0; u < 8; ++u) {
                    int q = (i + u < cB) ? (int)(unsigned short)rB[u] : duB;
                    vB[u] = sB[(q << 5) + sl];
                }
#pragma unroll
                for (int u = 0; u < 8; ++u) {
                    floatx2 lo = __builtin_amdgcn_cvt_pk_f32_fp8(vA[u], false);
                    floatx2 hi = __builtin_amdgcn_cvt_pk_f32_fp8(vA[u], true);
                    if (u & 1) { oA0 += lo; oA1 += hi; }
                    else       { eA0 += lo; eA1 += hi; }
                }
#pragma unroll
                for (int u = 0; u < 8; ++u) {
                    floatx2 lo = __builtin_amdgcn_cvt_pk_f32_fp8(vB[u], false);
                    floatx2 hi = __builtin_amdgcn_cvt_pk_f32_fp8(vB[u], true);
                    if (u & 1) { oB0 += lo; oB1 += hi; }
                    else       { eB0 += lo; eB1 += hi; }
                }
            }
            floatx2 sA0 = eA0 + oA0, sA1 = eA1 + oA1;
            floatx2 sB0 = eB0 + oB0, sB1 = eB1 + oB1;
            float sclA = dA > 0 ? 1.f / (float)dA : 0.f;
            float sclB = dB > 0 ? 1.f / (float)dB : 0.f;
            unsigned wloA = ((unsigned)f2bf(sA0.y * sclA) << 16) | (unsigned)f2bf(sA0.x * sclA);
            unsigned whiA = ((unsigned)f2bf(sA1.y * sclA) << 16) | (unsigned)f2bf(sA1.x * sclA);
            unsigned wloB = ((unsigned)f2bf(sB0.y * sclB) << 16) | (unsigned)f2bf(sB0.x * sclB);
            unsigned whiB = ((unsigned)f2bf(sB1.y * sclB) << 16) | (unsigned)f2bf(sB1.x * sclB);
            *(uint2*)&aggL[lA][sl * 4] = make_uint2(wloA, whiA);
            *(uint2*)&aggL[lB][sl * 4] = make_uint2(wloB, whiB);
        }
    }
    __syncthreads();
    // ---- GEMMs back-to-back ----
    int wave = tid >> 6, lane = tid & 63, ln = lane & 15, quad = lane >> 4;
    int wrow = (wave & 3) * 16, nhalf = wave >> 2;
    floatx4 acc[4];
#pragma unroll
    for (int t = 0; t < 4; ++t) acc[t] = (floatx4){0.f, 0.f, 0.f, 0.f};
    auto gemm_lds = [&](const unsigned short* __restrict__ Wb, int rowoff) {
#pragma unroll
        for (int kb = 0; kb < 4; ++kb) {
            short8 af = *(const short8*)&aggL[rowoff + wrow + ln][quad * 8 + kb * 32];
#pragma unroll
            for (int t = 0; t < 4; ++t) {
                short8 bf = *(const short8*)(Wb + ((nhalf * 4 + t) * 4 + kb) * 512 + lane * 8);
                acc[t] = __builtin_amdgcn_mfma_f32_16x16x32_bf16(af, bf, acc[t], 0, 0, 0);
            }
        }
    };
    auto gemm_glob = [&](const unsigned short* __restrict__ X,
                         const unsigned short* __restrict__ Wb) {
        int row = base + wrow + ln;
        int rowc = row < total ? row : total - 1;
        const unsigned short* A = X + (size_t)rowc * 128 + quad * 8;
#pragma unroll
        for (int kb = 0; kb < 4; ++kb) {
            short8 af = *(const short8*)(A + kb * 32);
#pragma unroll
            for (int t = 0; t < 4; ++t) {
                short8 bf = *(const short8*)(Wb + ((nhalf * 4 + t) * 4 + kb) * 512 + lane * 8);
                acc[t] = __builtin_amdgcn_mfma_f32_16x16x32_bf16(af, bf, acc[t], 0, 0, 0);
            }
        }
    };
    if (isPaper) {
        gemm_lds(Wp1, 0);                   // 0.5*Wl1[0] @ writes-agg (rows 0-63)
        gemm_lds(Wp1 + 16384, 64);          // 0.5*Wl1[1] @ cites-agg (rows 64-127)
        gemm_glob(xpb, Wp1 + 2 * 16384);    // 0.5*(Wr1[0]+Wr1[1]) @ x
    } else {
        gemm_lds(Wa1, 0);                   // Wl1[2] @ rev-agg
        gemm_glob(xab, Wa1 + 16384);        // Wr1[2] @ x
    }
    __syncthreads();
    // ---- epilogue: h = relu(acc + bias) -> aggL rows 0-63 (reused as hL) ----
    {
        const float* bias = isPaper ? bias_p1 : bias_a1;
#pragma unroll
        for (int t = 0; t < 4; ++t) {
            int col = nhalf * 64 + t * 16 + ln;
            float bv = bias[col];
#pragma unroll
            for (int r = 0; r < 4; ++r)
                aggL[wrow + quad * 4 + r][col] = f2bf(fmaxf(acc[t][r] + bv, 0.f));
        }
    }
    __syncthreads();
    // ---- transforms: t = h@Wt^T (+ sp = h@Wr2s^T for paper) ----
    floatx4 tacc[4];
#pragma unroll
    for (int t = 0; t < 4; ++t) tacc[t] = (floatx4){0.f, 0.f, 0.f, 0.f};
    int rows16 = (wave & 3) * 16;
    if (isPaper) {
        const unsigned short* W = (wave < 4) ? (Wt2 + 64 * 128) : Wr2s;
#pragma unroll
        for (int kb = 0; kb < 4; ++kb) {
            short8 af = *(const short8*)&aggL[rows16 + ln][quad * 8 + kb * 32];
#pragma unroll
            for (int t = 0; t < 4; ++t) {
                short8 bf = *(const short8*)(W + (t * 4 + kb) * 512 + lane * 8);
                tacc[t] = __builtin_amdgcn_mfma_f32_16x16x32_bf16(af, bf, tacc[t], 0, 0, 0);
            }
        }
#pragma unroll
        for (int t = 0; t < 4; ++t) {
            int col = t * 16 + ln;
#pragma unroll
            for (int r = 0; r < 4; ++r) {
                int lr = rows16 + quad * 4 + r;
                if (lr < M) {
                    if (wave < 4) tp[(size_t)(base + lr) * 64 + col] = f2bf(tacc[t][r]);
                    else sp[(size_t)(base + lr) * 64 + col] = tacc[t][r];
                }
            }
        }
    } else {
        int thalf = wave >> 2;
#pragma unroll
        for (int kb = 0; kb < 4; ++kb) {
            short8 af = *(const short8*)&aggL[rows16 + ln][quad * 8 + kb * 32];
#pragma unroll
            for (int tt = 0; tt < 2; ++tt) {
                short8 bf = *(const short8*)(Wt2 + ((thalf * 2 + tt) * 4 + kb) * 512 + lane * 8);
                tacc[tt] = __builtin_amdgcn_mfma_f32_16x16x32_bf16(af, bf, tacc[tt], 0, 0, 0);
            }
        }
#pragma unroll
        for (int tt = 0; tt < 2; ++tt) {
            int col = (thalf * 2 + tt) * 16 + ln;
#pragma unroll
            for (int r = 0; r < 4; ++r) {
                int lr = rows16 + quad * 4 + r;
                if (lr < M) ta[(size_t)(base + lr) * 64 + col] = f2bf(tacc[tt][r]);
            }
        }
    }
    // ---- spill cnt/csr node-major for paper (agg2 re-reads); drains at kernel end ----
    if (isPaper) {
        for (int r = tid; r < 2 * M; r += 512)
            cnt[base * 2 + r] = cursor[(r >> 1) + ((r & 1) << 6)];
        const unsigned* rU = (const unsigned*)rows;
        unsigned* cU = (unsigned*)csr + (size_t)base * 2 * (CAP / 2);
        for (int i = tid; i < 2 * M * (CAP / 2); i += 512) {
            int r = i / (CAP / 2), j = i - r * (CAP / 2);
            cU[i] = rU[((r >> 1) + ((r & 1) << 6)) * (CAP / 2) + j];
        }
    }
}

// ---------------- layer-2 aggregation + final epilogue: out = agg + sp + bias ----------
// Both relations merged (16 loads in flight/lane) + packed-f32 accumulation.
__global__ void agg2(const unsigned short* __restrict__ ta, const unsigned short* __restrict__ tp,
                     const int* __restrict__ cnt, const unsigned short* __restrict__ csr,
                     const float* __restrict__ sp_in, const float* __restrict__ bias_p2,
                     float* __restrict__ out) {
    int node = blockIdx.x * 8 + (threadIdx.x >> 5);
    if (node >= NP) return;
    int lane = threadIdx.x & 63;
    int sl = lane & 31;
    int hw = lane & 32;
    const unsigned* t0p = (const unsigned*)ta;
    const unsigned* t1p = (const unsigned*)tp;
    int deg0 = cnt[node * 2], deg1 = cnt[node * 2 + 1];
    int c0 = deg0 < CAP ? deg0 : CAP;
    int c1 = deg1 < CAP ? deg1 : CAP;
    const unsigned short* row0 = csr + (size_t)node * 2 * CAP;
    const unsigned short* row1 = row0 + CAP;
    int e00 = (sl < c0) ? (int)row0[sl] : NA;
    int e01 = (32 + sl < c0) ? (int)row0[32 + sl] : NA;
    int e10 = (sl < c1) ? (int)row1[sl] : NP;
    int e11 = (32 + sl < c1) ? (int)row1[32 + sl] : NP;
    int degw = c0 > c1 ? c0 : c1;
    int other = __shfl_xor(degw, 32, 64);
    if (other > degw) degw = other;
    floatx2 se = {0.f, 0.f}, so = {0.f, 0.f};   // rel0 even/odd chains (lo, hi)
    floatx2 ue = {0.f, 0.f}, uo = {0.f, 0.f};   // rel1 even/odd chains
    for (int i = 0; i < degw; i += 8) {
        unsigned v0[8], v1[8];
#pragma unroll
        for (int u = 0; u < 8; ++u) {
            int ii = i + u;
            int es = (ii < 32) ? e00 : e01;
            int qq = __shfl(es, hw | (ii & 31), 64);
            qq = (ii < c0) ? qq : NA;
            v0[u] = t0p[(qq << 5) + sl];
        }
#pragma unroll
        for (int u = 0; u < 8; ++u) {
            int ii = i + u;
            int es = (ii < 32) ? e10 : e11;
            int qq = __shfl(es, hw | (ii & 31), 64);
            qq = (ii < c1) ? qq : NP;
            v1[u] = t1p[(qq << 5) + sl];
        }
#pragma unroll
        for (int u = 0; u < 8; ++u) {
            floatx2 t = {bflo(v0[u]), bfhi(v0[u])};
            if (u & 1) so += t; else se += t;
        }
#pragma unroll
        for (int u = 0; u < 8; ++u) {
            floatx2 t = {bflo(v1[u]), bfhi(v1[u])};
            if (u & 1) uo += t; else ue += t;
        }
    }
    float scl0 = deg0 > 0 ? 1.f / (float)deg0 : 0.f;
    float scl1 = deg1 > 0 ? 1.f / (float)deg1 : 0.f;
    floatx2 s = se + so, u2 = ue + uo;
    float r0 = s.x * scl0 + u2.x * scl1;
    float r1 = s.y * scl0 + u2.y * scl1;
    float2 spv = ((const float2*)sp_in)[(size_t)node * 32 + sl];
    float2 bv = ((const float2*)bias_p2)[sl];
    ((float2*)out)[(size_t)node * 32 + sl] =
        make_float2(r0 + spv.x + bv.x, r1 + spv.y + bv.y);
}

// ---------------- launch ----------------
extern "C" void kernel_launch(void* const* d_in, const int* in_sizes, int n_in,
                              void* d_out, int out_size, void* d_ws, size_t ws_size,
                              hipStream_t stream) {
    (void)in_sizes; (void)n_in; (void)out_size; (void)ws_size;
    const float* xp  = (const float*)d_in[0];
    const float* xa  = (const float*)d_in[1];
    const float* Wl1 = (const float*)d_in[2];
    const float* bl1 = (const float*)d_in[3];
    const float* Wr1 = (const float*)d_in[4];
    const float* Wl2 = (const float*)d_in[5];
    const float* bl2 = (const float*)d_in[6];
    const float* Wr2 = (const float*)d_in[7];
    const int* w_src = (const int*)d_in[8];
    const int* w_dst = (const int*)d_in[9];
    const int* c_src = (const int*)d_in[10];
    const int* c_dst = (const int*)d_in[11];
    const int* r_src = (const int*)d_in[12];
    const int* r_dst = (const int*)d_in[13];
    float* out = (float*)d_out;

    char* p = (char*)d_ws;
    auto alloc = [&](size_t bytes) {
        char* r = p;
        p += (bytes + 255) & ~(size_t)255;
        return r;
    };
    unsigned short* xpb   = (unsigned short*)alloc((size_t)NP * 128 * 2);
    unsigned short* xab   = (unsigned short*)alloc((size_t)NA * 128 * 2);
    unsigned*       xp8   = (unsigned*)alloc((size_t)(NP + 1) * 128);  // +1 dummy zero row
    unsigned*       xa8   = (unsigned*)alloc((size_t)(NA + 1) * 128);  // +1 dummy zero row
    unsigned short* ta    = (unsigned short*)alloc((size_t)(NA + 1) * 64 * 2);  // +1 dummy
    unsigned short* tp    = (unsigned short*)alloc((size_t)(NP + 1) * 64 * 2);  // +1 dummy
    float*          sp    = (float*)alloc((size_t)NP * 64 * 4);
    int*            cnt     = (int*)alloc((size_t)NP * 2 * 4);
    unsigned short* csr     = (unsigned short*)alloc((size_t)NP * 2 * CAP * 2);
    unsigned*       seg     = (unsigned*)alloc((size_t)NSEG * RBLK * 4);
    unsigned*       segmeta = (unsigned*)alloc((size_t)NSEG * NBIN * 4);
    unsigned short* Wp1  = (unsigned short*)alloc(3 * 128 * 128 * 2);
    unsigned short* Wa1  = (unsigned short*)alloc(2 * 128 * 128 * 2);
    unsigned short* Wt2  = (unsigned short*)alloc(2 * 64 * 128 * 2);
    unsigned short* Wr2s = (unsigned short*)alloc(64 * 128 * 2);
    float* bias_p1 = (float*)alloc(128 * 4);
    float* bias_a1 = (float*)alloc(128 * 4);
    float* bias_p2 = (float*)alloc(64 * 4);

    // route (123 blocks @512 thr) + prep (incl. dummy-row zeroing) in one kernel
    int prep_threads = (NP + NA) * 32 + 106496 + 320 + 128;
    int prep_blocks = (prep_threads + 511) / 512;
    route_prep<<<NSEG + prep_blocks, 512, 0, stream>>>(
        xp, xa, Wl1, Wr1, Wl2, Wr2, bl1, bl2,
        xpb, xab, xp8, xa8, Wp1, Wa1, Wt2, Wr2s, bias_p1, bias_a1, bias_p2,
        w_src, w_dst, c_src, c_dst, r_src, r_dst, seg, segmeta, ta, tp);

    // fused CSR build + layer-1 agg + layer-1 GEMM + transforms
    fill_l1<<<NBIN, 512, 0, stream>>>(seg, segmeta, cnt, csr,
                                      xp8, xa8, xpb, xab, Wp1, bias_p1, Wa1, bias_a1,
                                      Wt2, Wr2s, ta, tp, sp);

    // layer-2 aggregation + final epilogue -> out
    agg2<<<(NP + 7) / 8, 256, 0, stream>>>(ta, tp, cnt, csr, sp, bias_p2, out);
}